// Round 1
// baseline (691.963 us; speedup 1.0000x reference)
//
#include <hip/hip_runtime.h>
#include <hip/hip_bf16.h>
#include <cstddef>

#define DIMC   768
#define HEADS  12
#define BATCH  4
#define SEQ    2048
#define MROWS  (BATCH * SEQ)      // 8192
#define NB_B   (HEADS * 32)       // 384  (Wb output width)

// ---------------------------------------------------------------------------
// Generic fp32 tiled GEMM: C[M,N] = A[M,K] @ B[K,N] (+ bias[N] if bias != 0)
// BM=BN=64, BK=16, 256 threads, 4x4 microtile per thread.
// Requires M%64==0, N%64==0, K%16==0 (true for all calls here).
// ---------------------------------------------------------------------------
__global__ __launch_bounds__(256)
void sgemm_kernel(const float* __restrict__ A, const float* __restrict__ B,
                  const float* __restrict__ bias, float* __restrict__ C,
                  int M, int N, int K)
{
    __shared__ float As[16][68];   // transposed A tile, +4 pad (bank-friendly, keeps 16B align)
    __shared__ float Bs[16][64];

    const int tid = threadIdx.x;
    const int tx = tid & 15;        // 0..15 -> N direction
    const int ty = tid >> 4;        // 0..15 -> M direction
    const int m0 = blockIdx.x * 64;
    const int n0 = blockIdx.y * 64;

    // A-tile load mapping: one float4 per thread. row = tid>>2 (0..63), k = (tid&3)*4
    const int am = tid >> 2;
    const int ak = (tid & 3) * 4;
    // B-tile load mapping: k = tid>>4 (0..15), n = (tid&15)*4
    const int bk = tid >> 4;
    const int bn = (tid & 15) * 4;

    float acc[4][4] = {};

    for (int k0 = 0; k0 < K; k0 += 16) {
        float4 av = *(const float4*)&A[(size_t)(m0 + am) * K + k0 + ak];
        float4 bv = *(const float4*)&B[(size_t)(k0 + bk) * N + n0 + bn];
        __syncthreads();   // protect previous iteration's LDS reads
        As[ak + 0][am] = av.x;
        As[ak + 1][am] = av.y;
        As[ak + 2][am] = av.z;
        As[ak + 3][am] = av.w;
        *(float4*)&Bs[bk][bn] = bv;
        __syncthreads();
#pragma unroll
        for (int kk = 0; kk < 16; ++kk) {
            float a0 = As[kk][ty * 4 + 0];
            float a1 = As[kk][ty * 4 + 1];
            float a2 = As[kk][ty * 4 + 2];
            float a3 = As[kk][ty * 4 + 3];
            float b0 = Bs[kk][tx * 4 + 0];
            float b1 = Bs[kk][tx * 4 + 1];
            float b2 = Bs[kk][tx * 4 + 2];
            float b3 = Bs[kk][tx * 4 + 3];
            acc[0][0] += a0 * b0; acc[0][1] += a0 * b1; acc[0][2] += a0 * b2; acc[0][3] += a0 * b3;
            acc[1][0] += a1 * b0; acc[1][1] += a1 * b1; acc[1][2] += a1 * b2; acc[1][3] += a1 * b3;
            acc[2][0] += a2 * b0; acc[2][1] += a2 * b1; acc[2][2] += a2 * b2; acc[2][3] += a2 * b3;
            acc[3][0] += a3 * b0; acc[3][1] += a3 * b1; acc[3][2] += a3 * b2; acc[3][3] += a3 * b3;
        }
    }

    float bias4[4] = {0.f, 0.f, 0.f, 0.f};
    if (bias) {
#pragma unroll
        for (int j = 0; j < 4; ++j) bias4[j] = bias[n0 + tx * 4 + j];
    }
#pragma unroll
    for (int i = 0; i < 4; ++i) {
        float4 o;
        o.x = acc[i][0] + bias4[0];
        o.y = acc[i][1] + bias4[1];
        o.z = acc[i][2] + bias4[2];
        o.w = acc[i][3] + bias4[3];
        *(float4*)&C[(size_t)(m0 + ty * 4 + i) * N + n0 + tx * 4] = o;
    }
}

// ---------------------------------------------------------------------------
// Pool V: Vs[(b*H+h)*64*64 + t*64 + d] = sum_{j=32t..32t+31} Yv[(b*SEQ+j)*768 + h*64 + d]
// ---------------------------------------------------------------------------
__global__ __launch_bounds__(256)
void pool_v_kernel(const float* __restrict__ Yv, float* __restrict__ Vs)
{
    int idx = blockIdx.x * 256 + threadIdx.x;      // 196608 total
    int d  = idx & 63;
    int t  = (idx >> 6) & 63;
    int bh = idx >> 12;
    int h = bh % HEADS, b = bh / HEADS;
    const float* src = Yv + (size_t)(b * SEQ + t * 32) * DIMC + h * 64 + d;
    float s = 0.f;
#pragma unroll
    for (int j = 0; j < 32; ++j) s += src[(size_t)j * DIMC];
    Vs[idx] = s;
}

// ---------------------------------------------------------------------------
// Attention: one wave per (b,h,i). lane k: s_k = a[k]*b[k/2]; softmax over 64
// (each logit represents 32 identical columns -> weight e_k/(32*sum));
// then lane d: out[d] = sum_k w_k * Vs[k][d]  (Vs staged in LDS per block).
// grid: (B*H, SEQ/64), block 256 (4 waves x 16 rows each).
// ---------------------------------------------------------------------------
__global__ __launch_bounds__(256)
void attn_kernel(const float* __restrict__ Ya, const float* __restrict__ Yb,
                 const float* __restrict__ Vs, float* __restrict__ Hout)
{
    __shared__ float vs[64 * 64];
    const int bh = blockIdx.x;
    const int h = bh % HEADS, b = bh / HEADS;

    for (int t = threadIdx.x; t < 64 * 64; t += 256)
        vs[t] = Vs[(size_t)bh * 4096 + t];
    __syncthreads();

    const int lane = threadIdx.x & 63;
    const int wave = threadIdx.x >> 6;

    for (int ii = 0; ii < 16; ++ii) {
        const int i = blockIdx.y * 64 + wave * 16 + ii;
        const size_t row = (size_t)(b * SEQ + i);
        float aval = Ya[row * DIMC + h * 64 + lane];
        float bval = Yb[row * NB_B + h * 32 + (lane >> 1)];
        float s = aval * bval;

        float m = s;
#pragma unroll
        for (int off = 32; off; off >>= 1) m = fmaxf(m, __shfl_xor(m, off, 64));
        float e = __expf(s - m);
        float sum = e;
#pragma unroll
        for (int off = 32; off; off >>= 1) sum += __shfl_xor(sum, off, 64);
        float w = e / (32.0f * sum);

        float acc = 0.f;
#pragma unroll
        for (int k = 0; k < 64; ++k)
            acc += __shfl(w, k, 64) * vs[k * 64 + lane];

        Hout[row * DIMC + h * 64 + lane] = acc;
    }
}

// ---------------------------------------------------------------------------
extern "C" void kernel_launch(void* const* d_in, const int* in_sizes, int n_in,
                              void* d_out, int out_size, void* d_ws, size_t ws_size,
                              hipStream_t stream)
{
    const float* x  = (const float*)d_in[0];   // (4,2048,768)
    const float* Wa = (const float*)d_in[1];   // (768,768)
    const float* Wb = (const float*)d_in[2];   // (768,384)
    const float* Wv = (const float*)d_in[3];   // (768,768)
    const float* Wp = (const float*)d_in[4];   // (768,768)
    const float* bp = (const float*)d_in[5];   // (768,)
    float* out = (float*)d_out;                // (4,2048,768)

    float* ws = (float*)d_ws;
    float* Ya = ws;                                   // 8192*768
    float* Yb = Ya + (size_t)MROWS * DIMC;            // 8192*384
    float* Yv = Yb + (size_t)MROWS * NB_B;            // 8192*768
    float* Vs = Yv + (size_t)MROWS * DIMC;            // 48*64*64
    float* Hout = Yv;   // alias: attn reads only Vs/Ya/Yb, so Yv space is reusable

    dim3 blk(256);

    // Stage A: three input GEMMs
    sgemm_kernel<<<dim3(MROWS / 64, DIMC / 64), blk, 0, stream>>>(x, Wa, nullptr, Ya, MROWS, DIMC, DIMC);
    sgemm_kernel<<<dim3(MROWS / 64, NB_B / 64), blk, 0, stream>>>(x, Wb, nullptr, Yb, MROWS, NB_B, DIMC);
    sgemm_kernel<<<dim3(MROWS / 64, DIMC / 64), blk, 0, stream>>>(x, Wv, nullptr, Yv, MROWS, DIMC, DIMC);

    // Stage B: pool V over 32-column blocks
    pool_v_kernel<<<dim3((BATCH * HEADS * 64 * 64) / 256), blk, 0, stream>>>(Yv, Vs);

    // Stage C: factorized softmax-attention (writes Hout over Yv space)
    attn_kernel<<<dim3(BATCH * HEADS, SEQ / 64), blk, 0, stream>>>(Ya, Yb, Vs, Hout);

    // Stage D: output projection + bias
    sgemm_kernel<<<dim3(MROWS / 64, DIMC / 64), blk, 0, stream>>>(Hout, Wp, bp, out, MROWS, DIMC, DIMC);
}

// Round 2
// 224.652 us; speedup vs baseline: 3.0802x; 3.0802x over previous
//
#include <hip/hip_runtime.h>
#include <hip/hip_bf16.h>
#include <cstddef>

#define DIMC   768
#define HEADS  12
#define BATCH  4
#define SEQ    2048
#define MROWS  (BATCH * SEQ)      // 8192
#define NCAT   1920               // 768 (Wa) + 384 (Wb) + 768 (Wv)
#define LDK    40                 // padded LDS K-stride (bf16 elems): 80 B, breaks 2^n stride

typedef unsigned short u16;
typedef __attribute__((ext_vector_type(8))) short short8;   // 8 bf16 = 4 VGPRs
typedef __attribute__((ext_vector_type(4))) float floatx4;  // MFMA C/D

__device__ inline u16 f2bf(float f) {
    union { float f; unsigned u; } v; v.f = f;
    unsigned u = v.u + 0x7FFF + ((v.u >> 16) & 1);   // RNE (no NaN handling needed)
    return (u16)(u >> 16);
}
__device__ inline float bf2f(u16 h) {
    union { unsigned u; float f; } v; v.u = ((unsigned)h) << 16;
    return v.f;
}

// ---------------------------------------------------------------------------
// x (fp32) -> xb (bf16), 8 elems/thread
// ---------------------------------------------------------------------------
__global__ __launch_bounds__(256)
void convert_x_kernel(const float* __restrict__ x, u16* __restrict__ xb)
{
    int i = blockIdx.x * 256 + threadIdx.x;          // < 786432
    const float4 f0 = ((const float4*)x)[(size_t)i * 2];
    const float4 f1 = ((const float4*)x)[(size_t)i * 2 + 1];
    u16 tmp[8] = { f2bf(f0.x), f2bf(f0.y), f2bf(f0.z), f2bf(f0.w),
                   f2bf(f1.x), f2bf(f1.y), f2bf(f1.z), f2bf(f1.w) };
    *(uint4*)&xb[(size_t)i * 8] = *(uint4*)tmp;
}

// ---------------------------------------------------------------------------
// Build transposed bf16 weights:
//  Wtcat[n][k] for n<1920 from [Wa|Wb|Wv];  Wpt[n][k] from Wp.
// Thread = (n, kchunk of 8). 1920*96 + 768*96 = 258048 threads.
// ---------------------------------------------------------------------------
__global__ __launch_bounds__(256)
void convert_w_kernel(const float* __restrict__ Wa, const float* __restrict__ Wb,
                      const float* __restrict__ Wv, const float* __restrict__ Wp,
                      u16* __restrict__ Wtcat, u16* __restrict__ Wpt)
{
    int idx = blockIdx.x * 256 + threadIdx.x;
    const int NC = NCAT * 96;    // 184320
    u16 tmp[8];
    if (idx < NC) {
        int n = idx / 96, kc = idx % 96;
        const float* src; int ld, col;
        if (n < 768)       { src = Wa; ld = 768; col = n; }
        else if (n < 1152) { src = Wb; ld = 384; col = n - 768; }
        else               { src = Wv; ld = 768; col = n - 1152; }
#pragma unroll
        for (int j = 0; j < 8; ++j) tmp[j] = f2bf(src[(size_t)(kc * 8 + j) * ld + col]);
        *(uint4*)&Wtcat[(size_t)n * DIMC + kc * 8] = *(uint4*)tmp;
    } else {
        int id2 = idx - NC;      // < 73728
        int n = id2 / 96, kc = id2 % 96;
#pragma unroll
        for (int j = 0; j < 8; ++j) tmp[j] = f2bf(Wp[(size_t)(kc * 8 + j) * DIMC + n]);
        *(uint4*)&Wpt[(size_t)n * DIMC + kc * 8] = *(uint4*)tmp;
    }
}

// ---------------------------------------------------------------------------
// bf16 MFMA GEMM: C[M,N] = A[M,K] @ Bt[N,K]^T (+bias), 128x128 tile, BK=32.
// 256 thr = 4 waves, each wave a 64x64 quadrant = 4x4 of 16x16x32 MFMA.
// A,Bt bf16; C fp32 or bf16.
// ---------------------------------------------------------------------------
template<bool WRITE_BF16>
__global__ __launch_bounds__(256)
void gemm_bf16_kernel(const u16* __restrict__ A, const u16* __restrict__ Bt,
                      const float* __restrict__ bias, void* __restrict__ Cout,
                      int K, int ldC)
{
    __shared__ u16 As[128 * LDK];
    __shared__ u16 Bs[128 * LDK];

    const int tid  = threadIdx.x;
    const int lane = tid & 63, wave = tid >> 6;
    const int quad = lane >> 4, l16 = lane & 15;
    const int wm = (wave & 1) * 64, wn = (wave >> 1) * 64;
    const int m0 = blockIdx.x * 128, n0 = blockIdx.y * 128;

    const int row0 = tid >> 2;      // 0..63
    const int colc = tid & 3;       // 16B chunk within BK=32 row

    floatx4 acc[4][4] = {};

    for (int k0 = 0; k0 < K; k0 += 32) {
        uint4 a0 = *(const uint4*)&A [(size_t)(m0 + row0     ) * K + k0 + colc * 8];
        uint4 a1 = *(const uint4*)&A [(size_t)(m0 + row0 + 64) * K + k0 + colc * 8];
        uint4 b0 = *(const uint4*)&Bt[(size_t)(n0 + row0     ) * K + k0 + colc * 8];
        uint4 b1 = *(const uint4*)&Bt[(size_t)(n0 + row0 + 64) * K + k0 + colc * 8];
        __syncthreads();
        *(uint4*)&As[(row0     ) * LDK + colc * 8] = a0;
        *(uint4*)&As[(row0 + 64) * LDK + colc * 8] = a1;
        *(uint4*)&Bs[(row0     ) * LDK + colc * 8] = b0;
        *(uint4*)&Bs[(row0 + 64) * LDK + colc * 8] = b1;
        __syncthreads();

        short8 af[4], bf[4];
#pragma unroll
        for (int t = 0; t < 4; ++t) {
            af[t] = *(short8*)&As[(wm + t * 16 + l16) * LDK + quad * 8];
            bf[t] = *(short8*)&Bs[(wn + t * 16 + l16) * LDK + quad * 8];
        }
#pragma unroll
        for (int mt = 0; mt < 4; ++mt)
#pragma unroll
            for (int nt = 0; nt < 4; ++nt)
                acc[mt][nt] = __builtin_amdgcn_mfma_f32_16x16x32_bf16(
                    af[mt], bf[nt], acc[mt][nt], 0, 0, 0);
    }

#pragma unroll
    for (int mt = 0; mt < 4; ++mt) {
#pragma unroll
        for (int nt = 0; nt < 4; ++nt) {
            const int gc = n0 + wn + nt * 16 + l16;
            const float bv = bias ? bias[gc] : 0.f;
#pragma unroll
            for (int r = 0; r < 4; ++r) {
                const int gr = m0 + wm + mt * 16 + quad * 4 + r;
                const float v = acc[mt][nt][r] + bv;
                if (WRITE_BF16) ((u16*)Cout)[(size_t)gr * ldC + gc] = f2bf(v);
                else            ((float*)Cout)[(size_t)gr * ldC + gc] = v;
            }
        }
    }
}

// ---------------------------------------------------------------------------
// Pool V (bf16 in, fp32 out): Vs[bh][t][d] = sum_{j=32t..32t+31} Yv[b, j, h*64+d]
// Yv = cols [1152,1920) of Ycat (row stride NCAT).
// ---------------------------------------------------------------------------
__global__ __launch_bounds__(256)
void pool_v_kernel(const u16* __restrict__ Ycat, float* __restrict__ Vs)
{
    int idx = blockIdx.x * 256 + threadIdx.x;     // < 196608
    int d  = idx & 63;
    int t  = (idx >> 6) & 63;
    int bh = idx >> 12;
    int h = bh % HEADS, b = bh / HEADS;
    const u16* src = Ycat + (size_t)(b * SEQ + t * 32) * NCAT + 1152 + h * 64 + d;
    float s = 0.f;
#pragma unroll
    for (int j = 0; j < 32; ++j) s += bf2f(src[(size_t)j * NCAT]);
    Vs[idx] = s;
}

// ---------------------------------------------------------------------------
// Attention: wave per (b,h,i-row). lane k: s_k = a[k]*b[k/2]; softmax over 64
// distinct logits (each stands for 32 equal columns -> w = e/(32*sum));
// out[d] = sum_k w_k * Vs[k][d]. Writes bf16 H for the final MFMA GEMM.
// ---------------------------------------------------------------------------
__global__ __launch_bounds__(256)
void attn_kernel(const u16* __restrict__ Ycat, const float* __restrict__ Vs,
                 u16* __restrict__ Hb)
{
    __shared__ float vs[64 * 64];
    __shared__ float wbuf[4][64];
    const int bh = blockIdx.x;
    const int h = bh % HEADS, b = bh / HEADS;

    for (int t = threadIdx.x; t < 64 * 64; t += 256)
        vs[t] = Vs[(size_t)bh * 4096 + t];
    __syncthreads();

    const int lane = threadIdx.x & 63;
    const int wave = threadIdx.x >> 6;

    for (int ii = 0; ii < 16; ++ii) {
        const int i = blockIdx.y * 64 + wave * 16 + ii;
        const size_t row = (size_t)(b * SEQ + i);
        float aval = bf2f(Ycat[row * NCAT + h * 64 + lane]);
        float bval = bf2f(Ycat[row * NCAT + 768 + h * 32 + (lane >> 1)]);
        float s = aval * bval;

        float m = s;
#pragma unroll
        for (int off = 32; off; off >>= 1) m = fmaxf(m, __shfl_xor(m, off, 64));
        float e = __expf(s - m);
        float sum = e;
#pragma unroll
        for (int off = 32; off; off >>= 1) sum += __shfl_xor(sum, off, 64);
        wbuf[wave][lane] = e / (32.0f * sum);
        __syncthreads();

        float acc = 0.f;
#pragma unroll
        for (int k = 0; k < 64; ++k)
            acc += wbuf[wave][k] * vs[k * 64 + lane];

        Hb[row * DIMC + h * 64 + lane] = f2bf(acc);
        __syncthreads();
    }
}

// ---------------------------------------------------------------------------
extern "C" void kernel_launch(void* const* d_in, const int* in_sizes, int n_in,
                              void* d_out, int out_size, void* d_ws, size_t ws_size,
                              hipStream_t stream)
{
    const float* x  = (const float*)d_in[0];
    const float* Wa = (const float*)d_in[1];
    const float* Wb = (const float*)d_in[2];
    const float* Wv = (const float*)d_in[3];
    const float* Wp = (const float*)d_in[4];
    const float* bp = (const float*)d_in[5];
    float* out = (float*)d_out;

    char* ws = (char*)d_ws;
    u16*   xb    = (u16*)ws;                                   ws += (size_t)MROWS * DIMC * 2;   // 12.6 MB
    u16*   Wtcat = (u16*)ws;                                   ws += (size_t)NCAT * DIMC * 2;    // 2.9 MB
    u16*   Wpt   = (u16*)ws;                                   ws += (size_t)DIMC * DIMC * 2;    // 1.2 MB
    u16*   Ycat  = (u16*)ws;                                   ws += (size_t)MROWS * NCAT * 2;   // 31.5 MB
    float* Vs    = (float*)ws;                                 ws += (size_t)48 * 4096 * 4;      // 0.8 MB
    u16*   Hb    = (u16*)ws;                                   // 12.6 MB   (total ~61.5 MB)

    dim3 blk(256);

    convert_x_kernel<<<dim3(MROWS * DIMC / 8 / 256), blk, 0, stream>>>(x, xb);
    convert_w_kernel<<<dim3((NCAT * 96 + DIMC * 96) / 256), blk, 0, stream>>>(Wa, Wb, Wv, Wp, Wtcat, Wpt);

    // fused input GEMM: Ycat[8192][1920] = x @ [Wa|Wb|Wv]  (bf16 out)
    gemm_bf16_kernel<true><<<dim3(MROWS / 128, NCAT / 128), blk, 0, stream>>>(
        xb, Wtcat, nullptr, Ycat, DIMC, NCAT);

    pool_v_kernel<<<dim3(BATCH * HEADS * 64 * 64 / 256), blk, 0, stream>>>(Ycat, Vs);

    attn_kernel<<<dim3(BATCH * HEADS, SEQ / 64), blk, 0, stream>>>(Ycat, Vs, Hb);

    // output projection: out = H @ Wp + bp  (fp32 out)
    gemm_bf16_kernel<false><<<dim3(MROWS / 128, DIMC / 128), blk, 0, stream>>>(
        Hb, Wpt, bp, out, DIMC, DIMC);
}

// Round 3
// 193.702 us; speedup vs baseline: 3.5723x; 1.1598x over previous
//
#include <hip/hip_runtime.h>
#include <hip/hip_bf16.h>
#include <cstddef>

#define DIMC   768
#define HEADS  12
#define BATCH  4
#define SEQ    2048
#define MROWS  (BATCH * SEQ)      // 8192
#define NCAT   1920               // 768 (Wa) + 384 (Wb) + 768 (Wv)

typedef unsigned short u16;
typedef __attribute__((ext_vector_type(8))) short short8;   // 8 bf16 = 4 VGPRs
typedef __attribute__((ext_vector_type(4))) float floatx4;  // MFMA C/D

__device__ inline u16 f2bf(float f) {
    union { float f; unsigned u; } v; v.f = f;
    unsigned u = v.u + 0x7FFF + ((v.u >> 16) & 1);   // RNE
    return (u16)(u >> 16);
}
__device__ inline float bf2f(u16 h) {
    union { unsigned u; float f; } v; v.u = ((unsigned)h) << 16;
    return v.f;
}

// async 16B/lane global->LDS. lptr must be the WAVE-UNIFORM segment base;
// HW scatters lane i to lptr + i*16.
__device__ inline void async_load16(const void* g, void* l) {
    __builtin_amdgcn_global_load_lds(
        (const __attribute__((address_space(1))) void*)g,
        (__attribute__((address_space(3))) void*)l, 16, 0, 0);
}

// ---------------------------------------------------------------------------
// x (fp32) -> xb (bf16), 8 elems/thread
// ---------------------------------------------------------------------------
__global__ __launch_bounds__(256)
void convert_x_kernel(const float* __restrict__ x, u16* __restrict__ xb)
{
    int i = blockIdx.x * 256 + threadIdx.x;          // < 786432
    const float4 f0 = ((const float4*)x)[(size_t)i * 2];
    const float4 f1 = ((const float4*)x)[(size_t)i * 2 + 1];
    u16 tmp[8] = { f2bf(f0.x), f2bf(f0.y), f2bf(f0.z), f2bf(f0.w),
                   f2bf(f1.x), f2bf(f1.y), f2bf(f1.z), f2bf(f1.w) };
    *(uint4*)&xb[(size_t)i * 8] = *(uint4*)tmp;
}

// ---------------------------------------------------------------------------
// Transposed bf16 weights via 64x64 LDS tile transpose (coalesced both sides).
// blocks 0..359: Wtcat (30 n-tiles x 12 k-tiles) from [Wa|Wb|Wv]
// blocks 360..503: Wpt (12 x 12) from Wp
// ---------------------------------------------------------------------------
__global__ __launch_bounds__(256)
void convert_w_kernel(const float* __restrict__ Wa, const float* __restrict__ Wb,
                      const float* __restrict__ Wv, const float* __restrict__ Wp,
                      u16* __restrict__ Wtcat, u16* __restrict__ Wpt)
{
    __shared__ u16 tile[64 * 72];   // [n][k], padded
    const int tid = threadIdx.x;
    int bid = blockIdx.x;
    const float* src; u16* dst; int n0, k0, ld, col0;
    if (bid < 360) {
        int nt = bid / 12, kt = bid % 12;
        n0 = nt * 64; k0 = kt * 64; dst = Wtcat;
        if (n0 < 768)       { src = Wa; ld = 768; col0 = n0; }
        else if (n0 < 1152) { src = Wb; ld = 384; col0 = n0 - 768; }
        else                { src = Wv; ld = 768; col0 = n0 - 1152; }
    } else {
        int b2 = bid - 360;
        int nt = b2 / 12, kt = b2 % 12;
        n0 = nt * 64; k0 = kt * 64; dst = Wpt; src = Wp; ld = 768; col0 = n0;
    }
#pragma unroll
    for (int p = 0; p < 16; ++p) {
        int i = p * 256 + tid;           // 4096
        int k = i >> 6, n = i & 63;      // coalesced read over n
        tile[n * 72 + k] = f2bf(src[(size_t)(k0 + k) * ld + col0 + n]);
    }
    __syncthreads();
    // write: thread -> row n = tid>>2, k-chunk (tid&3)*16, 16 bf16 = 32B
    int n = tid >> 2, kc = (tid & 3) * 16;
    uint4 o[2];
    o[0] = *(uint4*)&tile[n * 72 + kc];
    o[1] = *(uint4*)&tile[n * 72 + kc + 8];
    *(uint4*)&dst[(size_t)(n0 + n) * DIMC + k0 + kc] = o[0];
    *(uint4*)&dst[(size_t)(n0 + n) * DIMC + k0 + kc + 8] = o[1];
}

// ---------------------------------------------------------------------------
// bf16 MFMA GEMM (m97 structure): C[M,N] = A[M,K] @ Bt[N,K]^T (+bias).
// 128x128 tile, BK=32, 256 thr = 4 waves (64x64 quadrant each).
// global_load_lds width=16 staging into unpadded [row][32] LDS.
// ---------------------------------------------------------------------------
template<bool WRITE_BF16>
__global__ __launch_bounds__(256)
void gemm_bf16_kernel(const u16* __restrict__ A, const u16* __restrict__ Bt,
                      const float* __restrict__ bias, void* __restrict__ Cout,
                      int K, int ldC)
{
    __shared__ u16 As[128 * 32];
    __shared__ u16 Bs[128 * 32];

    const int tid  = threadIdx.x;
    const int lane = tid & 63, wave = tid >> 6;
    const int quad = lane >> 4, l16 = lane & 15;
    const int wm = (wave & 1) * 64, wn = (wave >> 1) * 64;
    const int m0 = blockIdx.x * 128, n0 = blockIdx.y * 128;

    // staging: wave stages rows [wave*32, wave*32+32) of A and B tiles,
    // 2 instructions of 16 rows each; lane -> row (lane>>2), 16B chunk (lane&3)
    const int lrow = lane >> 2, lchunk = lane & 3;
    const u16* gA = A  + (size_t)(m0 + wave * 32 + lrow) * K + lchunk * 8;
    const u16* gB = Bt + (size_t)(n0 + wave * 32 + lrow) * K + lchunk * 8;
    u16* lA = &As[wave * 32 * 32];
    u16* lB = &Bs[wave * 32 * 32];

    floatx4 acc[4][4] = {};

    for (int k0 = 0; k0 < K; k0 += 32) {
        __syncthreads();                       // prior frag reads done
        async_load16(gA + k0,          lA);
        async_load16(gA + k0 + 16 * K, lA + 16 * 32);
        async_load16(gB + k0,          lB);
        async_load16(gB + k0 + 16 * K, lB + 16 * 32);
        __syncthreads();                       // drains vmcnt -> LDS valid

        short8 af[4], bf[4];
#pragma unroll
        for (int t = 0; t < 4; ++t) {
            af[t] = *(short8*)&As[(wm + t * 16 + l16) * 32 + quad * 8];
            bf[t] = *(short8*)&Bs[(wn + t * 16 + l16) * 32 + quad * 8];
        }
#pragma unroll
        for (int mt = 0; mt < 4; ++mt)
#pragma unroll
            for (int nt = 0; nt < 4; ++nt)
                acc[mt][nt] = __builtin_amdgcn_mfma_f32_16x16x32_bf16(
                    af[mt], bf[nt], acc[mt][nt], 0, 0, 0);
    }

#pragma unroll
    for (int mt = 0; mt < 4; ++mt) {
#pragma unroll
        for (int nt = 0; nt < 4; ++nt) {
            const int gc = n0 + wn + nt * 16 + l16;
            const float bv = bias ? bias[gc] : 0.f;
#pragma unroll
            for (int r = 0; r < 4; ++r) {
                const int gr = m0 + wm + mt * 16 + quad * 4 + r;
                const float v = acc[mt][nt][r] + bv;
                if (WRITE_BF16) ((u16*)Cout)[(size_t)gr * ldC + gc] = f2bf(v);
                else            ((float*)Cout)[(size_t)gr * ldC + gc] = v;
            }
        }
    }
}

// ---------------------------------------------------------------------------
// Pool V: Vs[bh][t][d] = sum_{j=32t..32t+31} Ycat[b, j, 1152 + h*64 + d]  (fp32)
// ---------------------------------------------------------------------------
__global__ __launch_bounds__(256)
void pool_v_kernel(const u16* __restrict__ Ycat, float* __restrict__ Vs)
{
    int idx = blockIdx.x * 256 + threadIdx.x;     // < 196608
    int d  = idx & 63;
    int t  = (idx >> 6) & 63;
    int bh = idx >> 12;
    int h = bh % HEADS, b = bh / HEADS;
    const u16* src = Ycat + (size_t)(b * SEQ + t * 32) * NCAT + 1152 + h * 64 + d;
    float s = 0.f;
#pragma unroll
    for (int j = 0; j < 32; ++j) s += bf2f(src[(size_t)j * NCAT]);
    Vs[idx] = s;
}

// ---------------------------------------------------------------------------
// Attention via MFMA. Block = (bh, 64-row strip); wave owns 16 rows.
// lane=k softmax -> P row (bf16) into per-wave LDS (A-frag layout);
// Vs transposed to [d][k] bf16 in LDS; H_strip = P @ Vs via 8 MFMAs.
// No block barriers in the row loop (wlds is wave-private).
// ---------------------------------------------------------------------------
__global__ __launch_bounds__(256)
void attn_kernel(const u16* __restrict__ Ycat, const float* __restrict__ Vs,
                 u16* __restrict__ Hb)
{
    __shared__ u16 vsT[64 * 64];        // [d][k]
    __shared__ u16 wlds[4][16 * 64];    // per-wave P [r][k]
    const int bh = blockIdx.x;
    const int h = bh % HEADS, b = bh / HEADS;
    const int tid = threadIdx.x;

    for (int i = tid; i < 4096; i += 256) {           // read coalesced over d
        int t = i >> 6, d = i & 63;
        vsT[d * 64 + t] = f2bf(Vs[(size_t)bh * 4096 + i]);
    }
    __syncthreads();

    const int lane = tid & 63, wave = tid >> 6;
    const int quad = lane >> 4, l16 = lane & 15;

    // hoist B-fragments: bfrag[nt][kk][j] = Vs[k=kk*32+quad*8+j][d=nt*16+l16]
    short8 bfrag[4][2];
#pragma unroll
    for (int nt = 0; nt < 4; ++nt)
#pragma unroll
        for (int kk = 0; kk < 2; ++kk)
            bfrag[nt][kk] = *(short8*)&vsT[(nt * 16 + l16) * 64 + kk * 32 + quad * 8];

    const int i0 = blockIdx.y * 64 + wave * 16;       // strip base row

    for (int r = 0; r < 16; ++r) {
        const size_t row = (size_t)(b * SEQ + i0 + r);
        float aval = bf2f(Ycat[row * NCAT + h * 64 + lane]);
        float bval = bf2f(Ycat[row * NCAT + 768 + h * 32 + (lane >> 1)]);
        float s = aval * bval;
        float m = s;
#pragma unroll
        for (int off = 32; off; off >>= 1) m = fmaxf(m, __shfl_xor(m, off, 64));
        float e = __expf(s - m);
        float sum = e;
#pragma unroll
        for (int off = 32; off; off >>= 1) sum += __shfl_xor(sum, off, 64);
        wlds[wave][r * 64 + lane] = f2bf(e / (32.0f * sum));
    }

    short8 af0 = *(short8*)&wlds[wave][l16 * 64 + quad * 8];
    short8 af1 = *(short8*)&wlds[wave][l16 * 64 + 32 + quad * 8];

    floatx4 acc[4] = {};
#pragma unroll
    for (int nt = 0; nt < 4; ++nt) {
        acc[nt] = __builtin_amdgcn_mfma_f32_16x16x32_bf16(af0, bfrag[nt][0], acc[nt], 0, 0, 0);
        acc[nt] = __builtin_amdgcn_mfma_f32_16x16x32_bf16(af1, bfrag[nt][1], acc[nt], 0, 0, 0);
    }

#pragma unroll
    for (int nt = 0; nt < 4; ++nt)
#pragma unroll
        for (int rr = 0; rr < 4; ++rr) {
            const size_t row = (size_t)(b * SEQ + i0 + quad * 4 + rr);
            Hb[row * DIMC + h * 64 + nt * 16 + l16] = f2bf(acc[nt][rr]);
        }
}

// ---------------------------------------------------------------------------
extern "C" void kernel_launch(void* const* d_in, const int* in_sizes, int n_in,
                              void* d_out, int out_size, void* d_ws, size_t ws_size,
                              hipStream_t stream)
{
    const float* x  = (const float*)d_in[0];
    const float* Wa = (const float*)d_in[1];
    const float* Wb = (const float*)d_in[2];
    const float* Wv = (const float*)d_in[3];
    const float* Wp = (const float*)d_in[4];
    const float* bp = (const float*)d_in[5];
    float* out = (float*)d_out;

    char* ws = (char*)d_ws;
    u16*   xb    = (u16*)ws;   ws += (size_t)MROWS * DIMC * 2;
    u16*   Wtcat = (u16*)ws;   ws += (size_t)NCAT * DIMC * 2;
    u16*   Wpt   = (u16*)ws;   ws += (size_t)DIMC * DIMC * 2;
    u16*   Ycat  = (u16*)ws;   ws += (size_t)MROWS * NCAT * 2;
    float* Vs    = (float*)ws; ws += (size_t)48 * 4096 * 4;
    u16*   Hb    = (u16*)ws;

    dim3 blk(256);

    convert_x_kernel<<<dim3(MROWS * DIMC / 8 / 256), blk, 0, stream>>>(x, xb);
    convert_w_kernel<<<dim3(504), blk, 0, stream>>>(Wa, Wb, Wv, Wp, Wtcat, Wpt);

    gemm_bf16_kernel<true><<<dim3(MROWS / 128, NCAT / 128), blk, 0, stream>>>(
        xb, Wtcat, nullptr, Ycat, DIMC, NCAT);

    pool_v_kernel<<<dim3(BATCH * HEADS * 64 * 64 / 256), blk, 0, stream>>>(Ycat, Vs);

    attn_kernel<<<dim3(BATCH * HEADS, SEQ / 64), blk, 0, stream>>>(Ycat, Vs, Hb);

    gemm_bf16_kernel<false><<<dim3(MROWS / 128, DIMC / 128), blk, 0, stream>>>(
        Hb, Wpt, bp, out, DIMC, DIMC);
}